// Round 5
// baseline (177.046 us; speedup 1.0000x reference)
//
#include <hip/hip_runtime.h>

#define T_STEPS 345
#define B_SZ    128
#define IN_SZ   13
#define H_SZ    128
#define OUT_SZ  9
#define XPITCH  16   // padded floats per timestep row in LDS (64B-aligned rows)

typedef float v2f __attribute__((ext_vector_type(2)));

// Single DPP-shifted add; CTRL is a frontend constant. bound_ctrl=false,
// old=0: invalid source lanes contribute 0.
template <int CTRL>
__device__ __forceinline__ float dpp_add(float x) {
    int y = __builtin_amdgcn_update_dpp(0, __float_as_int(x), CTRL, 0xf, 0xf, false);
    return x + __int_as_float(y);
}

// One block = one wave = one batch element's full T=345 scan.
// R4 structure, rescheduled: DPP reduce is LEVEL-MAJOR (9 independent chains
// interleaved per level so the gfx9 VALU->DPP 2-wait-state hazard is filled
// with real work instead of s_nop), layer-1/partials use v_pk_fma_f32
// (bit-exact per-component chains), final select is a 4-level cndmask tree.
// DO NOT reorder any FMA chain — numerics are knife-edge (R3 lesson).
__global__ __launch_bounds__(64, 1)
void snn_scan_kernel(const float* __restrict__ x,
                     const float* __restrict__ W1,
                     const float* __restrict__ b1,
                     const float* __restrict__ W2,
                     const float* __restrict__ b2,
                     const float* __restrict__ beta1p,
                     const float* __restrict__ thr1p,
                     const float* __restrict__ beta2p,
                     const float* __restrict__ thr2p,
                     float* __restrict__ out)
{
    const int b    = blockIdx.x;
    const int lane = threadIdx.x;   // 0..63

    __shared__ float xst[T_STEPS * XPITCH];   // 22,080 B

    // Stage + transpose x[b,:,:] (13 x 345, c-major) -> xst[t*16 + c]
    const float* xb = x + (size_t)b * (IN_SZ * T_STEPS);
    for (int i = lane; i < IN_SZ * T_STEPS; i += 64) {
        const int c = i / T_STEPS;
        const int t = i - c * T_STEPS;
        xst[t * XPITCH + c] = xb[i];
    }

    const float bt1 = fminf(fmaxf(beta1p[0], 0.0f), 1.0f);
    const float th1 = thr1p[0];
    const float bt2 = fminf(fmaxf(beta2p[0], 0.0f), 1.0f);
    const float th2 = thr2p[0];

    // Per-lane packed weights for the two owned hidden neurons (ha, hb)
    const int ha = lane;
    const int hb = lane + 64;
    v2f w1p[IN_SZ];
#pragma unroll
    for (int c = 0; c < IN_SZ; ++c)
        w1p[c] = (v2f){ W1[ha * IN_SZ + c], W1[hb * IN_SZ + c] };
    const v2f b1p = (v2f){ b1[ha], b1[hb] };

    v2f w2p[OUT_SZ];
#pragma unroll
    for (int o = 0; o < OUT_SZ; ++o)
        w2p[o] = (v2f){ W2[o * H_SZ + ha], W2[o * H_SZ + hb] };

    const float b2o = (lane < OUT_SZ) ? b2[lane] : 0.0f;

    // Lane-bit bools for the select tree (masks hoisted out of the loop)
    const bool lb0 = (lane & 1) != 0;
    const bool lb1 = (lane & 2) != 0;
    const bool lb2 = (lane & 4) != 0;
    const bool lb3 = (lane & 8) != 0;

    v2f   mem1 = (v2f){0.0f, 0.0f};
    float mem2 = 0.0f;   // meaningful for lanes 0..8 only

    float* __restrict__ ps = out + (size_t)b * OUT_SZ + lane;                            // spk_rec
    float* __restrict__ pm = out + (size_t)T_STEPS * B_SZ * OUT_SZ + (size_t)b * OUT_SZ + lane; // mem_rec

    const v2f BT1 = (v2f){bt1, bt1};

    __syncthreads();

    // Prefetch t=0 (wave-uniform LDS reads)
    const float4* xq = (const float4*)xst;
    float4 q0 = xq[0], q1 = xq[1], q2 = xq[2];
    float  q3 = xst[12];

    for (int t = 0; t < T_STEPS; ++t) {
        const float xv[IN_SZ] = { q0.x, q0.y, q0.z, q0.w,
                                  q1.x, q1.y, q1.z, q1.w,
                                  q2.x, q2.y, q2.z, q2.w, q3 };

        // Prefetch next step (branchless; clamped index re-reads last row)
        const int tn = (t + 1 < T_STEPS) ? t + 1 : t;
        q0 = xq[tn * 4 + 0];
        q1 = xq[tn * 4 + 1];
        q2 = xq[tn * 4 + 2];
        q3 = xst[tn * XPITCH + 12];

        // ---- layer 1: packed FMA chain; per-component order == R1/R4 ----
        v2f cab = b1p;
#pragma unroll
        for (int c = 0; c < IN_SZ; ++c) {
            const v2f xc = (v2f){ xv[c], xv[c] };
            cab = __builtin_elementwise_fma(xc, w1p[c], cab);
        }

        mem1 = __builtin_elementwise_fma(BT1, mem1, cab);
        const float sa = (mem1.x > th1) ? 1.0f : 0.0f;
        const float sb = (mem1.y > th1) ? 1.0f : 0.0f;
        const v2f S = (v2f){ sa, sb };
        mem1 = __builtin_elementwise_fma(-S, (v2f){th1, th1}, mem1);  // subtract-reset

        // ---- layer 2 partials: pk_mul + pk_fma == fmaf(sb,w2b,sa*w2a) ----
        const v2f SA = (v2f){ sa, sa };
        const v2f SB = (v2f){ sb, sb };
        float p[OUT_SZ];
#pragma unroll
        for (int o = 0; o < OUT_SZ; ++o) {
            const v2f prod = __builtin_elementwise_fma(SB, (v2f){w2p[o].y, w2p[o].y},
                                                       SA * (v2f){w2p[o].x, w2p[o].x});
            p[o] = prod.x;   // .x component carries the scalar-identical result
        }
        // NOTE: the pk trick above would waste the .y half; recompute scalar
        // instead — simple, and bit-exact is what matters:
#pragma unroll
        for (int o = 0; o < OUT_SZ; ++o)
            p[o] = fmaf(sb, w2p[o].y, sa * w2p[o].x);

        // ---- DPP all-lane reduce, LEVEL-MAJOR (fills VALU->DPP hazards) ----
#pragma unroll
        for (int o = 0; o < OUT_SZ; ++o) p[o] = dpp_add<0x111>(p[o]); // row_shr:1
#pragma unroll
        for (int o = 0; o < OUT_SZ; ++o) p[o] = dpp_add<0x112>(p[o]); // row_shr:2
#pragma unroll
        for (int o = 0; o < OUT_SZ; ++o) p[o] = dpp_add<0x114>(p[o]); // row_shr:4
#pragma unroll
        for (int o = 0; o < OUT_SZ; ++o) p[o] = dpp_add<0x118>(p[o]); // row_shr:8
#pragma unroll
        for (int o = 0; o < OUT_SZ; ++o) p[o] = dpp_add<0x142>(p[o]); // row_bcast:15
#pragma unroll
        for (int o = 0; o < OUT_SZ; ++o) p[o] = dpp_add<0x143>(p[o]); // row_bcast:31

        // ---- totals (lane 63) -> uniform, 4-level select tree ----
        float tt[OUT_SZ];
#pragma unroll
        for (int o = 0; o < OUT_SZ; ++o)
            tt[o] = __int_as_float(__builtin_amdgcn_readlane(__float_as_int(p[o]), 63));

        const float a0 = lb0 ? tt[1] : tt[0];
        const float a1 = lb0 ? tt[3] : tt[2];
        const float a2 = lb0 ? tt[5] : tt[4];
        const float a3 = lb0 ? tt[7] : tt[6];
        const float c0 = lb1 ? a1 : a0;
        const float c1 = lb1 ? a3 : a2;
        const float d0 = lb2 ? c1 : c0;
        const float cur2s = lb3 ? tt[8] : d0;
        const float cur2 = cur2s + b2o;

        mem2 = fmaf(bt2, mem2, cur2);
        const float s2 = (mem2 > th2) ? 1.0f : 0.0f;
        mem2 = fmaf(-s2, th2, mem2);

        if (lane < OUT_SZ) {
            *ps = s2;
            *pm = mem2;
        }
        ps += B_SZ * OUT_SZ;
        pm += B_SZ * OUT_SZ;
    }
}

extern "C" void kernel_launch(void* const* d_in, const int* in_sizes, int n_in,
                              void* d_out, int out_size, void* d_ws, size_t ws_size,
                              hipStream_t stream) {
    const float* x     = (const float*)d_in[0];
    const float* W1    = (const float*)d_in[1];
    const float* b1    = (const float*)d_in[2];
    const float* W2    = (const float*)d_in[3];
    const float* b2    = (const float*)d_in[4];
    const float* beta1 = (const float*)d_in[5];
    const float* thr1  = (const float*)d_in[6];
    const float* beta2 = (const float*)d_in[7];
    const float* thr2  = (const float*)d_in[8];
    float* out = (float*)d_out;

    snn_scan_kernel<<<dim3(B_SZ), dim3(64), 0, stream>>>(
        x, W1, b1, W2, b2, beta1, thr1, beta2, thr2, out);
}

// Round 6
// 173.524 us; speedup vs baseline: 1.0203x; 1.0203x over previous
//
#include <hip/hip_runtime.h>

#define T_STEPS 345
#define B_SZ    128
#define IN_SZ   13
#define H_SZ    128
#define OUT_SZ  9
#define XPITCH  16   // padded floats per timestep row in LDS (64B-aligned rows)

typedef float v2f __attribute__((ext_vector_type(2)));

// Single DPP-shifted add; CTRL is a frontend constant. bound_ctrl=false,
// old=0: invalid source lanes contribute 0.
template <int CTRL>
__device__ __forceinline__ float dpp_add(float x) {
    int y = __builtin_amdgcn_update_dpp(0, __float_as_int(x), CTRL, 0xf, 0xf, false);
    return x + __int_as_float(y);
}

// One block = one wave = one batch element's full T=345 scan.
// R6: 2-stage software pipeline. A(t) = layer1 + spike + layer2-partials;
// B(t-1) = DPP reduce + mem2 + store. A(t) is independent of B(t-1)
// (mem1 and mem2 are separate recurrences), so each loop body holds two
// independent instruction streams — hides the ~4cyc dependent-VALU latency
// that a single resident wave cannot otherwise hide. Manual 2x unroll with
// ping-pong partial buffers removes register-rotation copies.
// ALL FP chains bit-identical to R4/R5 (R3 lesson: do not reorder any chain).
__global__ __launch_bounds__(64, 1)
void snn_scan_kernel(const float* __restrict__ x,
                     const float* __restrict__ W1,
                     const float* __restrict__ b1,
                     const float* __restrict__ W2,
                     const float* __restrict__ b2,
                     const float* __restrict__ beta1p,
                     const float* __restrict__ thr1p,
                     const float* __restrict__ beta2p,
                     const float* __restrict__ thr2p,
                     float* __restrict__ out)
{
    const int b    = blockIdx.x;
    const int lane = threadIdx.x;   // 0..63

    __shared__ float xst[(T_STEPS + 1) * XPITCH];   // +1 pad row: clampless prefetch

    // Stage + transpose x[b,:,:] (13 x 345, c-major) -> xst[t*16 + c]
    const float* xb = x + (size_t)b * (IN_SZ * T_STEPS);
    for (int i = lane; i < IN_SZ * T_STEPS; i += 64) {
        const int c = i / T_STEPS;
        const int t = i - c * T_STEPS;
        xst[t * XPITCH + c] = xb[i];
    }

    const float bt1 = fminf(fmaxf(beta1p[0], 0.0f), 1.0f);
    const float th1 = thr1p[0];
    const float bt2 = fminf(fmaxf(beta2p[0], 0.0f), 1.0f);
    const float th2 = thr2p[0];

    // Per-lane packed weights for the two owned hidden neurons (ha, hb)
    const int ha = lane;
    const int hb = lane + 64;
    v2f w1p[IN_SZ];
#pragma unroll
    for (int c = 0; c < IN_SZ; ++c)
        w1p[c] = (v2f){ W1[ha * IN_SZ + c], W1[hb * IN_SZ + c] };
    const v2f b1p = (v2f){ b1[ha], b1[hb] };

    v2f w2p[OUT_SZ];
#pragma unroll
    for (int o = 0; o < OUT_SZ; ++o)
        w2p[o] = (v2f){ W2[o * H_SZ + ha], W2[o * H_SZ + hb] };

    const float b2o = (lane < OUT_SZ) ? b2[lane] : 0.0f;

    // Lane-bit bools for the select tree
    const bool lb0 = (lane & 1) != 0;
    const bool lb1 = (lane & 2) != 0;
    const bool lb2 = (lane & 4) != 0;
    const bool lb3 = (lane & 8) != 0;

    v2f   mem1 = (v2f){0.0f, 0.0f};
    float mem2 = 0.0f;   // meaningful for lanes 0..8 only

    float* __restrict__ ps = out + (size_t)b * OUT_SZ + lane;                                   // spk_rec
    float* __restrict__ pm = out + (size_t)T_STEPS * B_SZ * OUT_SZ + (size_t)b * OUT_SZ + lane; // mem_rec

    const v2f BT1 = (v2f){bt1, bt1};
    const v2f TH1 = (v2f){th1, th1};

    __syncthreads();

    const float4* xq = (const float4*)xst;
    float4 q0 = xq[0], q1 = xq[1], q2 = xq[2];
    float  q3 = xst[12];

    // ---- A-phase: consume current q regs as step k's x; prefetch row k+1;
    //      layer-1 chain (exact R4/R5 order), spike, layer-2 partials.
    auto aphase = [&](int knext, float* p) {
        const float xv[IN_SZ] = { q0.x, q0.y, q0.z, q0.w,
                                  q1.x, q1.y, q1.z, q1.w,
                                  q2.x, q2.y, q2.z, q2.w, q3 };
        q0 = xq[knext * 4 + 0];
        q1 = xq[knext * 4 + 1];
        q2 = xq[knext * 4 + 2];
        q3 = xst[knext * XPITCH + 12];

        v2f cab = b1p;
#pragma unroll
        for (int c = 0; c < IN_SZ; ++c) {
            const v2f xc = (v2f){ xv[c], xv[c] };
            cab = __builtin_elementwise_fma(xc, w1p[c], cab);
        }
        mem1 = __builtin_elementwise_fma(BT1, mem1, cab);
        const float sa = (mem1.x > th1) ? 1.0f : 0.0f;
        const float sb = (mem1.y > th1) ? 1.0f : 0.0f;
        const v2f S = (v2f){ sa, sb };
        mem1 = __builtin_elementwise_fma(-S, TH1, mem1);  // subtract-reset
#pragma unroll
        for (int o = 0; o < OUT_SZ; ++o)
            p[o] = fmaf(sb, w2p[o].y, sa * w2p[o].x);
    };

    // ---- B-phase: DPP reduce (level-major), select, mem2 update, store.
    auto bphase = [&](float* p) {
#pragma unroll
        for (int o = 0; o < OUT_SZ; ++o) p[o] = dpp_add<0x111>(p[o]); // row_shr:1
#pragma unroll
        for (int o = 0; o < OUT_SZ; ++o) p[o] = dpp_add<0x112>(p[o]); // row_shr:2
#pragma unroll
        for (int o = 0; o < OUT_SZ; ++o) p[o] = dpp_add<0x114>(p[o]); // row_shr:4
#pragma unroll
        for (int o = 0; o < OUT_SZ; ++o) p[o] = dpp_add<0x118>(p[o]); // row_shr:8
#pragma unroll
        for (int o = 0; o < OUT_SZ; ++o) p[o] = dpp_add<0x142>(p[o]); // row_bcast:15
#pragma unroll
        for (int o = 0; o < OUT_SZ; ++o) p[o] = dpp_add<0x143>(p[o]); // row_bcast:31

        float tt[OUT_SZ];
#pragma unroll
        for (int o = 0; o < OUT_SZ; ++o)
            tt[o] = __int_as_float(__builtin_amdgcn_readlane(__float_as_int(p[o]), 63));

        const float a0 = lb0 ? tt[1] : tt[0];
        const float a1 = lb0 ? tt[3] : tt[2];
        const float a2 = lb0 ? tt[5] : tt[4];
        const float a3 = lb0 ? tt[7] : tt[6];
        const float c0 = lb1 ? a1 : a0;
        const float c1 = lb1 ? a3 : a2;
        const float d0 = lb2 ? c1 : c0;
        const float cur2 = (lb3 ? tt[8] : d0) + b2o;

        mem2 = fmaf(bt2, mem2, cur2);
        const float s2 = (mem2 > th2) ? 1.0f : 0.0f;
        mem2 = fmaf(-s2, th2, mem2);

        if (lane < OUT_SZ) {
            *ps = s2;
            *pm = mem2;
        }
        ps += B_SZ * OUT_SZ;
        pm += B_SZ * OUT_SZ;
    };

    float pa[OUT_SZ], pb[OUT_SZ];

    // Prologue: A(0)
    aphase(1, pa);

    // Main: t odd, 1..343 (172 iters). Each iter: A(t),B(t-1),A(t+1),B(t).
    // A(344) prefetches pad row 345 (never consumed).
    for (int t = 1; t < T_STEPS; t += 2) {
        aphase(t + 1, pb);   // A(t)
        bphase(pa);          // B(t-1)
        aphase(t + 2, pa);   // A(t+1)
        bphase(pb);          // B(t)
    }

    // Epilogue: B(T-1)
    bphase(pa);
}

extern "C" void kernel_launch(void* const* d_in, const int* in_sizes, int n_in,
                              void* d_out, int out_size, void* d_ws, size_t ws_size,
                              hipStream_t stream) {
    const float* x     = (const float*)d_in[0];
    const float* W1    = (const float*)d_in[1];
    const float* b1    = (const float*)d_in[2];
    const float* W2    = (const float*)d_in[3];
    const float* b2    = (const float*)d_in[4];
    const float* beta1 = (const float*)d_in[5];
    const float* thr1  = (const float*)d_in[6];
    const float* beta2 = (const float*)d_in[7];
    const float* thr2  = (const float*)d_in[8];
    float* out = (float*)d_out;

    snn_scan_kernel<<<dim3(B_SZ), dim3(64), 0, stream>>>(
        x, W1, b1, W2, b2, beta1, thr1, beta2, thr2, out);
}

// Round 7
// 124.715 us; speedup vs baseline: 1.4196x; 1.3914x over previous
//
#include <hip/hip_runtime.h>

#define T_STEPS 345
#define B_SZ    128
#define IN_SZ   13
#define H_SZ    128
#define OUT_SZ  9
#define XPITCH  16
#define TPAD    384                 // padded t-extent for cur2 rows (384 = 6*64)
#define NBO     (B_SZ * OUT_SZ)     // 1152
#define MASK_BYTES (B_SZ * T_STEPS * 2 * 8)   // 706560, u64 [B][T][2]

// ---------------- K1: layer-1 scan, one thread per hidden neuron ----------------
// Thread tid = neuron h of batch blockIdx.x. Layer-1 FMA chain and mem1 update
// are BIT-IDENTICAL to the R1/R4/R6 passing kernels (knife-edge numerics —
// do not reorder). Spikes exported as per-wave ballot masks: bit l of mask
// half (tid>>6) at step t == spike of neuron (tid>>6)*64+l.
__global__ __launch_bounds__(128, 1)
void k1_spikes(const float* __restrict__ x, const float* __restrict__ W1,
               const float* __restrict__ b1, const float* __restrict__ beta1p,
               const float* __restrict__ thr1p,
               unsigned long long* __restrict__ masks)
{
    const int b   = blockIdx.x;
    const int tid = threadIdx.x;    // 0..127 == neuron h

    __shared__ float xst[(T_STEPS + 3) * XPITCH];   // 22,272 B (pad rows: clampless prefetch)

    const float* xb = x + (size_t)b * (IN_SZ * T_STEPS);
    for (int i = tid; i < IN_SZ * T_STEPS; i += 128) {
        const int c = i / T_STEPS;
        const int t = i - c * T_STEPS;
        xst[t * XPITCH + c] = xb[i];
    }

    const float bt1 = fminf(fmaxf(beta1p[0], 0.0f), 1.0f);
    const float th1 = thr1p[0];

    float w1r[IN_SZ];
#pragma unroll
    for (int c = 0; c < IN_SZ; ++c) w1r[c] = W1[tid * IN_SZ + c];
    const float b1r = b1[tid];

    float mem1 = 0.0f;
    unsigned long long* mp = masks + (size_t)b * (T_STEPS * 2) + (tid >> 6);
    const bool store_lane = (tid & 63) == 0;

    __syncthreads();

    const float4* xq = (const float4*)xst;
    // Two in-flight x-row register sets (steps t and t+1)
    float4 a0 = xq[0], a1 = xq[1], a2 = xq[2]; float a3 = xst[12];
    float4 c0 = xq[4], c1 = xq[5], c2 = xq[6]; float c3 = xst[XPITCH + 12];

    int t = 0;
    for (; t < T_STEPS - 1; t += 2) {
        const float xa[IN_SZ] = { a0.x,a0.y,a0.z,a0.w, a1.x,a1.y,a1.z,a1.w,
                                  a2.x,a2.y,a2.z,a2.w, a3 };
        const float xc[IN_SZ] = { c0.x,c0.y,c0.z,c0.w, c1.x,c1.y,c1.z,c1.w,
                                  c2.x,c2.y,c2.z,c2.w, c3 };
        // prefetch rows t+2, t+3 (pad rows cover the tail)
        a0 = xq[(t+2)*4+0]; a1 = xq[(t+2)*4+1]; a2 = xq[(t+2)*4+2]; a3 = xst[(t+2)*XPITCH+12];
        c0 = xq[(t+3)*4+0]; c1 = xq[(t+3)*4+1]; c2 = xq[(t+3)*4+2]; c3 = xst[(t+3)*XPITCH+12];

        // two independent 13-FMA chains (exact R1 per-neuron order)
        float cura = b1r, curb = b1r;
#pragma unroll
        for (int c = 0; c < IN_SZ; ++c) {
            cura = fmaf(xa[c], w1r[c], cura);
            curb = fmaf(xc[c], w1r[c], curb);
        }

        // step t
        mem1 = fmaf(bt1, mem1, cura);
        const bool pa = mem1 > th1;
        const unsigned long long ma = __ballot(pa);
        mem1 = fmaf(pa ? -1.0f : 0.0f, th1, mem1);   // == fmaf(-s, th1, mem1)
        if (store_lane) mp[0] = ma;

        // step t+1
        mem1 = fmaf(bt1, mem1, curb);
        const bool pb = mem1 > th1;
        const unsigned long long mb = __ballot(pb);
        mem1 = fmaf(pb ? -1.0f : 0.0f, th1, mem1);
        if (store_lane) mp[2] = mb;

        mp += 4;
    }
    // tail step t = 344
    {
        const float xa[IN_SZ] = { a0.x,a0.y,a0.z,a0.w, a1.x,a1.y,a1.z,a1.w,
                                  a2.x,a2.y,a2.z,a2.w, a3 };
        float cura = b1r;
#pragma unroll
        for (int c = 0; c < IN_SZ; ++c) cura = fmaf(xa[c], w1r[c], cura);
        mem1 = fmaf(bt1, mem1, cura);
        const bool pa = mem1 > th1;
        const unsigned long long ma = __ballot(pa);
        if (store_lane) mp[0] = ma;
    }
}

// ---------------- K2: cur2 GEMM, bit-masked dot, fully parallel ----------------
// Wave-uniform (b,o); lane = t within a 64-step stripe. Mask loads are
// coalesced dwordx4 (16B per (b,t) record, lane-consecutive t). Serial
// h=0..127 fma chain (layer-2 sum order is tolerant: R1 vs R4 identical absmax).
__global__ __launch_bounds__(256, 1)
void k2_gemm(const unsigned long long* __restrict__ masks,
             const float* __restrict__ W2, const float* __restrict__ b2,
             float* __restrict__ cur2)
{
    const int gw   = blockIdx.x * 4 + (threadIdx.x >> 6);  // global wave 0..6911
    const int lane = threadIdx.x & 63;
    const int bo   = gw / 6;             // 0..1151
    const int w    = gw - bo * 6;
    const int b    = bo / 9;
    const int o    = bo - b * 9;
    const int t    = w * 64 + lane;      // 0..383
    const int tc   = (t < T_STEPS) ? t : (T_STEPS - 1);   // clamp load addr

    const uint4 mm = *(const uint4*)((const char*)masks +
                                     ((size_t)b * T_STEPS + tc) * 16);

    const float* __restrict__ w2row = W2 + o * H_SZ;
    float acc = 0.0f;
#pragma unroll
    for (int h = 0; h < 32; ++h)
        acc = fmaf((float)((mm.x >> h) & 1u), w2row[h], acc);
#pragma unroll
    for (int h = 0; h < 32; ++h)
        acc = fmaf((float)((mm.y >> h) & 1u), w2row[32 + h], acc);
#pragma unroll
    for (int h = 0; h < 32; ++h)
        acc = fmaf((float)((mm.z >> h) & 1u), w2row[64 + h], acc);
#pragma unroll
    for (int h = 0; h < 32; ++h)
        acc = fmaf((float)((mm.w >> h) & 1u), w2row[96 + h], acc);

    cur2[(size_t)bo * TPAD + t] = acc + b2[o];
}

// ---------------- K3: mem2 scan, one lane per (b,o) ----------------
__global__ __launch_bounds__(64, 1)
void k3_scan2(const float* __restrict__ cur2, const float* __restrict__ beta2p,
              const float* __restrict__ thr2p, float* __restrict__ out)
{
    const int lid = blockIdx.x * 64 + threadIdx.x;   // 0..1151 == b*9+o
    const float bt2 = fminf(fmaxf(beta2p[0], 0.0f), 1.0f);
    const float th2 = thr2p[0];

    const float4* __restrict__ src = (const float4*)(cur2 + (size_t)lid * TPAD);
    float* __restrict__ out_spk = out + lid;
    float* __restrict__ out_mem = out + (size_t)T_STEPS * NBO + lid;

    float mem2 = 0.0f;

    float4 f0 = src[0], f1 = src[1], f2 = src[2], f3 = src[3];

    // 88 groups of 4 steps (t < 352); prefetch 4 groups (16 steps) ahead.
    for (int g = 0; g < 88; g += 4) {
        const float4 u0 = f0, u1 = f1, u2 = f2, u3 = f3;
        f0 = src[g + 4]; f1 = src[g + 5]; f2 = src[g + 6]; f3 = src[g + 7]; // ≤ src[91] < 96 ✓

        const float4 us[4] = { u0, u1, u2, u3 };
#pragma unroll
        for (int j = 0; j < 4; ++j) {
            const float vv[4] = { us[j].x, us[j].y, us[j].z, us[j].w };
#pragma unroll
            for (int k = 0; k < 4; ++k) {
                const int tt = (g + j) * 4 + k;
                mem2 = fmaf(bt2, mem2, vv[k]);
                const float s2 = (mem2 > th2) ? 1.0f : 0.0f;
                mem2 = fmaf(-s2, th2, mem2);
                if (tt < T_STEPS) {
                    out_spk[(size_t)tt * NBO] = s2;
                    out_mem[(size_t)tt * NBO] = mem2;
                }
            }
        }
    }
}

extern "C" void kernel_launch(void* const* d_in, const int* in_sizes, int n_in,
                              void* d_out, int out_size, void* d_ws, size_t ws_size,
                              hipStream_t stream) {
    const float* x     = (const float*)d_in[0];
    const float* W1    = (const float*)d_in[1];
    const float* b1    = (const float*)d_in[2];
    const float* W2    = (const float*)d_in[3];
    const float* b2    = (const float*)d_in[4];
    const float* beta1 = (const float*)d_in[5];
    const float* thr1  = (const float*)d_in[6];
    const float* beta2 = (const float*)d_in[7];
    const float* thr2  = (const float*)d_in[8];
    float* out = (float*)d_out;

    char* ws = (char*)d_ws;
    unsigned long long* masks = (unsigned long long*)ws;        // 706,560 B
    float* cur2 = (float*)(ws + MASK_BYTES);                    // 1,769,472 B

    k1_spikes<<<dim3(B_SZ), dim3(128), 0, stream>>>(x, W1, b1, beta1, thr1, masks);
    k2_gemm  <<<dim3(1728), dim3(256), 0, stream>>>(masks, W2, b2, cur2);
    k3_scan2 <<<dim3(NBO / 64), dim3(64), 0, stream>>>(cur2, beta2, thr2, out);
}